// Round 5
// baseline (172.315 us; speedup 1.0000x reference)
//
#include <hip/hip_runtime.h>

#define PRO_NUM 64
#define TERM_NUM 512
#define MAX_LEN 1024
#define HID 256

typedef _Float16 f16x8 __attribute__((ext_vector_type(8)));
typedef _Float16 f16x4 __attribute__((ext_vector_type(4)));
typedef float f32x4 __attribute__((ext_vector_type(4)));

// Fragment layouts (all f16x8 = 16B chunks, lane-major innermost => coalesced):
//   fragP[p(64)][T(64)][kk(8)][lane(64)]  : QK^T B-op. chunk = pro[p][T*16+lr][kk*32+lg*8 ..+8]
//   fragT[p(64)][H(16)][kc(32)][lane(64)] : PV  B-op. chunk = pro[p][kc*32+lg*8 ..+8][H*16+lr]
// where lr = lane&15, lg = lane>>4.

__device__ __forceinline__ f16x8 cvt8(const float* __restrict__ s) {
  float4 a = *(const float4*)s;
  float4 b = *(const float4*)(s + 4);
  f16x8 r = {(_Float16)a.x, (_Float16)a.y, (_Float16)a.z, (_Float16)a.w,
             (_Float16)b.x, (_Float16)b.y, (_Float16)b.z, (_Float16)b.w};
  return r;
}

// K1: pro f32 -> fragP + fragT (fragment-ordered f16). Block = (p, 64-l chunk).
__global__ __launch_bounds__(256) void k_prep(const float* __restrict__ pro,
                                              f16x8* __restrict__ fragP,
                                              f16x8* __restrict__ fragT) {
  __shared__ _Float16 ldsA[64][264];  // 64 l x 256 h, +8 pad
  const int p = blockIdx.y;
  const int lc = blockIdx.x;
  const int tid = threadIdx.x;

  const float* src = pro + ((size_t)p * MAX_LEN + lc * 64) * HID;
  #pragma unroll
  for (int j = 0; j < 16; ++j) {
    int idx = j * 1024 + tid * 4;
    int l = idx >> 8, h = idx & 255;
    float4 v = *(const float4*)(src + idx);
    ldsA[l][h + 0] = (_Float16)v.x;
    ldsA[l][h + 1] = (_Float16)v.y;
    ldsA[l][h + 2] = (_Float16)v.z;
    ldsA[l][h + 3] = (_Float16)v.w;
  }
  __syncthreads();

  const int w = tid >> 6;
  const int lane = tid & 63;
  const int lr = lane & 15;
  const int lg = lane >> 4;

  // fragP: wave w owns local l-tile w (global T = lc*4 + w)
  {
    const int T = lc * 4 + w;
    f16x8* dst = fragP + ((size_t)(p * 64 + T) * 8) * 64 + lane;
    #pragma unroll
    for (int kk = 0; kk < 8; ++kk)
      dst[kk * 64] = *(const f16x8*)&ldsA[w * 16 + lr][kk * 32 + lg * 8];
  }
  // fragT: wave w owns H in [w*4, w*4+4), kc in {lc*2, lc*2+1}
  #pragma unroll
  for (int hh = 0; hh < 4; ++hh) {
    const int H = w * 4 + hh;
    #pragma unroll
    for (int k2 = 0; k2 < 2; ++k2) {
      const int kc = lc * 2 + k2;
      const int lloc = k2 * 32 + lg * 8;
      f16x8 v;
      #pragma unroll
      for (int i = 0; i < 8; ++i) v[i] = ldsA[lloc + i][H * 16 + lr];
      fragT[((size_t)(p * 16 + H) * 32 + kc) * 64 + lane] = v;
    }
  }
}

// K2 (fused): per (p, 16-term tile): QK^T -> masked softmax -> LDS attn (f16, swizzled)
// -> coalesced attn writeback (f32) -> PV from LDS -> out.
// 2048 blocks, small LDS (34 KB) + small acc (64 VGPR) => 4 waves/SIMD, ~4 blocks/CU.
__global__ __launch_bounds__(256, 4) void k_fused(
    const float* __restrict__ term, const f16x8* __restrict__ fragP,
    const f16x8* __restrict__ fragT, const int* __restrict__ lens,
    float* __restrict__ attn, float* __restrict__ out) {
  __shared__ __align__(16) _Float16 attn_lds[16][1024];  // 32 KB, XOR-swizzled cols
  __shared__ float rmx[4][16];
  __shared__ float rsm[4][16];

  // XCD-chunked swizzle: all 32 t-tiles of a p stay on one XCD
  const int bid = blockIdx.x;
  const int swz = (bid & 7) * 256 + (bid >> 3);
  const int p = swz >> 5;
  const int t0 = (swz & 31) * 16;

  const int tid = threadIdx.x;
  const int w = tid >> 6;
  const int lane = tid & 63;
  const int lr = lane & 15;
  const int lg = lane >> 4;
  const int len = lens[p];
  const int l0w = w * 256;

  // ---------------- Phase A: scores = term @ pro^T (branchless, pipelined) ----------------
  f32x4 acc[16];
  #pragma unroll
  for (int i = 0; i < 16; ++i) acc[i] = (f32x4){0.f, 0.f, 0.f, 0.f};

  const float* trow0 = term + (size_t)(t0 + lr) * HID + lg * 8;
  const f16x8* pbw = fragP + ((size_t)(p * 64 + w * 16) * 8) * 64 + lane;

  #pragma unroll
  for (int kk = 0; kk < 8; ++kk) {
    f16x8 a0 = cvt8(trow0 + kk * 32);
    #pragma unroll
    for (int g = 0; g < 4; ++g) {
      f16x8 bf[4];
      #pragma unroll
      for (int t = 0; t < 4; ++t) bf[t] = pbw[((g * 4 + t) * 8 + kk) * 64];
      #pragma unroll
      for (int t = 0; t < 4; ++t)
        acc[g * 4 + t] = __builtin_amdgcn_mfma_f32_16x16x32_f16(a0, bf[t], acc[g * 4 + t], 0, 0, 0);
    }
  }

  // ---------------- Phase B: masked softmax ----------------
  float rmax[4] = {-INFINITY, -INFINITY, -INFINITY, -INFINITY};
  #pragma unroll
  for (int tile = 0; tile < 16; ++tile) {
    int l = l0w + tile * 16 + lr;
    #pragma unroll
    for (int r = 0; r < 4; ++r) {
      float s = (l < len) ? acc[tile][r] : -INFINITY;
      acc[tile][r] = s;
      rmax[r] = fmaxf(rmax[r], s);
    }
  }
  #pragma unroll
  for (int m = 1; m < 16; m <<= 1) {
    #pragma unroll
    for (int r = 0; r < 4; ++r) rmax[r] = fmaxf(rmax[r], __shfl_xor(rmax[r], m));
  }
  if (lr == 0) {
    #pragma unroll
    for (int r = 0; r < 4; ++r) rmx[w][lg * 4 + r] = rmax[r];
  }
  __syncthreads();
  float fm[4];
  #pragma unroll
  for (int r = 0; r < 4; ++r) {
    int row = lg * 4 + r;
    fm[r] = fmaxf(fmaxf(rmx[0][row], rmx[1][row]), fmaxf(rmx[2][row], rmx[3][row]));
  }
  float rsum[4] = {0.f, 0.f, 0.f, 0.f};
  #pragma unroll
  for (int tile = 0; tile < 16; ++tile) {
    #pragma unroll
    for (int r = 0; r < 4; ++r) {
      float e = __expf(acc[tile][r] - fm[r]);  // masked -> 0
      acc[tile][r] = e;
      rsum[r] += e;
    }
  }
  #pragma unroll
  for (int m = 1; m < 16; m <<= 1) {
    #pragma unroll
    for (int r = 0; r < 4; ++r) rsum[r] += __shfl_xor(rsum[r], m);
  }
  if (lr == 0) {
    #pragma unroll
    for (int r = 0; r < 4; ++r) rsm[w][lg * 4 + r] = rsum[r];
  }
  __syncthreads();
  float inv[4];
  #pragma unroll
  for (int r = 0; r < 4; ++r) {
    int row = lg * 4 + r;
    inv[r] = 1.0f / (rsm[0][row] + rsm[1][row] + rsm[2][row] + rsm[3][row]);
  }

  // normalized attn -> LDS (f16, swizzled)
  #pragma unroll
  for (int r = 0; r < 4; ++r) {
    const int row = lg * 4 + r;
    const int sw = (row & 7) << 3;
    #pragma unroll
    for (int tile = 0; tile < 16; ++tile) {
      attn_lds[row][(l0w + tile * 16 + lr) ^ sw] = (_Float16)(acc[tile][r] * inv[r]);
    }
  }
  __syncthreads();

  // coalesced attn writeback: wave w owns rows w*4..w*4+3 (row = w*4+lg);
  // lane lr covers cols j*256 + lr*16 .. +16
  {
    const int row = w * 4 + lg;
    const int sw = (row & 7) << 3;
    float* arow = attn + ((size_t)(p * TERM_NUM + t0 + row)) * MAX_LEN;
    #pragma unroll
    for (int j = 0; j < 4; ++j) {
      const int c0 = j * 256 + lr * 16;
      f16x8 v0 = *(const f16x8*)&attn_lds[row][c0 ^ sw];
      f16x8 v1 = *(const f16x8*)&attn_lds[row][(c0 + 8) ^ sw];
      float4 o;
      o = (float4){(float)v0[0], (float)v0[1], (float)v0[2], (float)v0[3]};
      *(float4*)(arow + c0 + 0) = o;
      o = (float4){(float)v0[4], (float)v0[5], (float)v0[6], (float)v0[7]};
      *(float4*)(arow + c0 + 4) = o;
      o = (float4){(float)v1[0], (float)v1[1], (float)v1[2], (float)v1[3]};
      *(float4*)(arow + c0 + 8) = o;
      o = (float4){(float)v1[4], (float)v1[5], (float)v1[6], (float)v1[7]};
      *(float4*)(arow + c0 + 12) = o;
    }
  }

  // ---------------- Phase C: out = attn @ pro ----------------
  f32x4 acc2[4];
  #pragma unroll
  for (int nt = 0; nt < 4; ++nt) acc2[nt] = (f32x4){0.f, 0.f, 0.f, 0.f};

  const f16x8* btw = fragT + ((size_t)(p * 16 + w * 4) * 32) * 64 + lane;
  const int kcmax = (len + 31) >> 5;

  #pragma unroll 4
  for (int kc = 0; kc < kcmax; ++kc) {
    const int k0 = kc * 32;
    const int row = lr;
    f16x8 a = *(const f16x8*)&attn_lds[row][(k0 + lg * 8) ^ ((row & 7) << 3)];
    #pragma unroll
    for (int nt = 0; nt < 4; ++nt) {
      f16x8 bf = btw[(nt * 32 + kc) * 64];
      acc2[nt] = __builtin_amdgcn_mfma_f32_16x16x32_f16(a, bf, acc2[nt], 0, 0, 0);
    }
  }

  #pragma unroll
  for (int nt = 0; nt < 4; ++nt) {
    #pragma unroll
    for (int r = 0; r < 4; ++r) {
      out[((size_t)p * TERM_NUM + t0 + lg * 4 + r) * HID + w * 64 + nt * 16 + lr] = acc2[nt][r];
    }
  }
}

extern "C" void kernel_launch(void* const* d_in, const int* in_sizes, int n_in,
                              void* d_out, int out_size, void* d_ws, size_t ws_size,
                              hipStream_t stream) {
  const float* term = (const float*)d_in[0];           // 512 x 256
  const float* pro  = (const float*)d_in[1];           // 64 x 1024 x 256
  const int*   lens = (const int*)d_in[2];             // 64

  float* out  = (float*)d_out;                                   // 64*512*256
  float* attn = out + (size_t)PRO_NUM * TERM_NUM * HID;          // 64*512*1024

  f16x8* fragP = (f16x8*)d_ws;                                   // 33.55 MB
  f16x8* fragT = fragP + (size_t)PRO_NUM * 64 * 8 * 64;          // 33.55 MB

  k_prep<<<dim3(MAX_LEN / 64, PRO_NUM), 256, 0, stream>>>(pro, fragP, fragT);
  k_fused<<<dim3(PRO_NUM * (TERM_NUM / 16)), 256, 0, stream>>>(term, fragP, fragT, lens, attn, out);
}

// Round 6
// 130.990 us; speedup vs baseline: 1.3155x; 1.3155x over previous
//
#include <hip/hip_runtime.h>

#define PRO_NUM 64
#define TERM_NUM 512
#define MAX_LEN 1024
#define HID 256

typedef _Float16 f16x8 __attribute__((ext_vector_type(8)));
typedef _Float16 f16x4 __attribute__((ext_vector_type(4)));
typedef float f32x4 __attribute__((ext_vector_type(4)));

// Fragment layouts (all f16x8 = 16B chunks, lane-major innermost => coalesced):
//   fragP[p(64)][T(64)][kk(8)][lane(64)]  : QK^T B-op. chunk = pro[p][T*16+lr][kk*32+lg*8 ..+8]
//   fragT[p(64)][H(16)][kc(32)][lane(64)] : PV  B-op. chunk = pro[p][kc*32+lg*8 ..+8][H*16+lr]
// where lr = lane&15, lg = lane>>4.

__device__ __forceinline__ f16x8 cvt8(const float* __restrict__ s) {
  float4 a = *(const float4*)s;
  float4 b = *(const float4*)(s + 4);
  f16x8 r = {(_Float16)a.x, (_Float16)a.y, (_Float16)a.z, (_Float16)a.w,
             (_Float16)b.x, (_Float16)b.y, (_Float16)b.z, (_Float16)b.w};
  return r;
}

// K1: pro f32 -> fragP + fragT (fragment-ordered f16). Block = (p, 64-l chunk).
__global__ __launch_bounds__(256) void k_prep(const float* __restrict__ pro,
                                              f16x8* __restrict__ fragP,
                                              f16x8* __restrict__ fragT) {
  __shared__ _Float16 ldsA[64][264];  // 64 l x 256 h, +8 pad
  const int p = blockIdx.y;
  const int lc = blockIdx.x;
  const int tid = threadIdx.x;

  const float* src = pro + ((size_t)p * MAX_LEN + lc * 64) * HID;
  #pragma unroll
  for (int j = 0; j < 16; ++j) {
    int idx = j * 1024 + tid * 4;
    int l = idx >> 8, h = idx & 255;
    float4 v = *(const float4*)(src + idx);
    ldsA[l][h + 0] = (_Float16)v.x;
    ldsA[l][h + 1] = (_Float16)v.y;
    ldsA[l][h + 2] = (_Float16)v.z;
    ldsA[l][h + 3] = (_Float16)v.w;
  }
  __syncthreads();

  const int w = tid >> 6;
  const int lane = tid & 63;
  const int lr = lane & 15;
  const int lg = lane >> 4;

  // fragP: wave w owns local l-tile w (global T = lc*4 + w)
  {
    const int T = lc * 4 + w;
    f16x8* dst = fragP + ((size_t)(p * 64 + T) * 8) * 64 + lane;
    #pragma unroll
    for (int kk = 0; kk < 8; ++kk)
      dst[kk * 64] = *(const f16x8*)&ldsA[w * 16 + lr][kk * 32 + lg * 8];
  }
  // fragT: wave w owns H in [w*4, w*4+4), kc in {lc*2, lc*2+1}
  #pragma unroll
  for (int hh = 0; hh < 4; ++hh) {
    const int H = w * 4 + hh;
    #pragma unroll
    for (int k2 = 0; k2 < 2; ++k2) {
      const int kc = lc * 2 + k2;
      const int lloc = k2 * 32 + lg * 8;
      f16x8 v;
      #pragma unroll
      for (int i = 0; i < 8; ++i) v[i] = ldsA[lloc + i][H * 16 + lr];
      fragT[((size_t)(p * 16 + H) * 32 + kc) * 64 + lane] = v;
    }
  }
}

// K2 (fused): per (p, 32-term tile): QK^T -> masked softmax -> write attn (nt stores,
// f32 global + f16 LDS swizzled) -> PV from LDS -> write out (nt).
// attn/out are write-once streams: non-temporal stores keep them from thrashing L2,
// so fragP/fragT stay L2-resident for the deep phase-A load pipeline.
__global__ __launch_bounds__(256) void k_fused(
    const float* __restrict__ term, const f16x8* __restrict__ fragP,
    const f16x8* __restrict__ fragT, const int* __restrict__ lens,
    float* __restrict__ attn, float* __restrict__ out) {
  __shared__ __align__(16) _Float16 attn_lds[32][1024];  // 64 KB, XOR-swizzled cols
  __shared__ float rmx[4][32];
  __shared__ float rsm[4][32];

  // XCD-chunked swizzle: all 16 t-tiles of a p stay on one XCD
  const int bid = blockIdx.x;
  const int swz = (bid & 7) * 128 + (bid >> 3);
  const int p = swz >> 4;
  const int t0 = (swz & 15) * 32;

  const int tid = threadIdx.x;
  const int w = tid >> 6;
  const int lane = tid & 63;
  const int lr = lane & 15;
  const int lg = lane >> 4;
  const int len = lens[p];
  const int l0w = w * 256;

  // ---------------- Phase A: scores = term @ pro^T (branchless, pipelined) ----------------
  f32x4 acc[2][16];
  #pragma unroll
  for (int mt = 0; mt < 2; ++mt)
    #pragma unroll
    for (int i = 0; i < 16; ++i) acc[mt][i] = (f32x4){0.f, 0.f, 0.f, 0.f};

  const float* trow0 = term + (size_t)(t0 + lr) * HID + lg * 8;
  const f16x8* pbw = fragP + ((size_t)(p * 64 + w * 16) * 8) * 64 + lane;

  #pragma unroll
  for (int kk = 0; kk < 8; ++kk) {
    f16x8 a0 = cvt8(trow0 + kk * 32);
    f16x8 a1 = cvt8(trow0 + (size_t)16 * HID + kk * 32);
    f16x8 bf[16];
    #pragma unroll
    for (int tile = 0; tile < 16; ++tile) bf[tile] = pbw[(tile * 8 + kk) * 64];
    #pragma unroll
    for (int tile = 0; tile < 16; ++tile) {
      acc[0][tile] = __builtin_amdgcn_mfma_f32_16x16x32_f16(a0, bf[tile], acc[0][tile], 0, 0, 0);
      acc[1][tile] = __builtin_amdgcn_mfma_f32_16x16x32_f16(a1, bf[tile], acc[1][tile], 0, 0, 0);
    }
  }

  // ---------------- Phase B: masked softmax ----------------
  float rmax[2][4];
  #pragma unroll
  for (int mt = 0; mt < 2; ++mt)
    #pragma unroll
    for (int r = 0; r < 4; ++r) rmax[mt][r] = -INFINITY;

  #pragma unroll
  for (int tile = 0; tile < 16; ++tile) {
    int l = l0w + tile * 16 + lr;
    #pragma unroll
    for (int mt = 0; mt < 2; ++mt) {
      #pragma unroll
      for (int r = 0; r < 4; ++r) {
        float s = (l < len) ? acc[mt][tile][r] : -INFINITY;
        acc[mt][tile][r] = s;
        rmax[mt][r] = fmaxf(rmax[mt][r], s);
      }
    }
  }
  #pragma unroll
  for (int m = 1; m < 16; m <<= 1) {
    #pragma unroll
    for (int mt = 0; mt < 2; ++mt)
      #pragma unroll
      for (int r = 0; r < 4; ++r) rmax[mt][r] = fmaxf(rmax[mt][r], __shfl_xor(rmax[mt][r], m));
  }
  if (lr == 0) {
    #pragma unroll
    for (int mt = 0; mt < 2; ++mt)
      #pragma unroll
      for (int r = 0; r < 4; ++r) rmx[w][mt * 16 + lg * 4 + r] = rmax[mt][r];
  }
  __syncthreads();
  float fm[2][4];
  #pragma unroll
  for (int mt = 0; mt < 2; ++mt)
    #pragma unroll
    for (int r = 0; r < 4; ++r) {
      int row = mt * 16 + lg * 4 + r;
      fm[mt][r] = fmaxf(fmaxf(rmx[0][row], rmx[1][row]), fmaxf(rmx[2][row], rmx[3][row]));
    }

  float rsum[2][4] = {{0.f, 0.f, 0.f, 0.f}, {0.f, 0.f, 0.f, 0.f}};
  #pragma unroll
  for (int tile = 0; tile < 16; ++tile) {
    #pragma unroll
    for (int mt = 0; mt < 2; ++mt) {
      #pragma unroll
      for (int r = 0; r < 4; ++r) {
        float e = __expf(acc[mt][tile][r] - fm[mt][r]);  // masked -> 0
        acc[mt][tile][r] = e;
        rsum[mt][r] += e;
      }
    }
  }
  #pragma unroll
  for (int m = 1; m < 16; m <<= 1) {
    #pragma unroll
    for (int mt = 0; mt < 2; ++mt)
      #pragma unroll
      for (int r = 0; r < 4; ++r) rsum[mt][r] += __shfl_xor(rsum[mt][r], m);
  }
  if (lr == 0) {
    #pragma unroll
    for (int mt = 0; mt < 2; ++mt)
      #pragma unroll
      for (int r = 0; r < 4; ++r) rsm[w][mt * 16 + lg * 4 + r] = rsum[mt][r];
  }
  __syncthreads();
  float inv[2][4];
  #pragma unroll
  for (int mt = 0; mt < 2; ++mt)
    #pragma unroll
    for (int r = 0; r < 4; ++r) {
      int row = mt * 16 + lg * 4 + r;
      inv[mt][r] = 1.0f / (rsm[0][row] + rsm[1][row] + rsm[2][row] + rsm[3][row]);
    }

  // write attn to global (f32, non-temporal) and LDS (f16, swizzled) in one pass
  #pragma unroll
  for (int mt = 0; mt < 2; ++mt) {
    #pragma unroll
    for (int r = 0; r < 4; ++r) {
      const int row = mt * 16 + lg * 4 + r;
      float* arow = attn + ((size_t)(p * TERM_NUM + t0 + row)) * MAX_LEN + l0w + lr;
      const int sw = (row & 7) << 3;
      #pragma unroll
      for (int tile = 0; tile < 16; ++tile) {
        float v = acc[mt][tile][r] * inv[mt][r];
        __builtin_nontemporal_store(v, &arow[tile * 16]);
        attn_lds[row][(l0w + tile * 16 + lr) ^ sw] = (_Float16)v;
      }
    }
  }
  __syncthreads();

  // ---------------- Phase C: out = attn @ pro ----------------
  f32x4 acc2[2][4];
  #pragma unroll
  for (int mt = 0; mt < 2; ++mt)
    #pragma unroll
    for (int nt = 0; nt < 4; ++nt) acc2[mt][nt] = (f32x4){0.f, 0.f, 0.f, 0.f};

  const f16x8* btw = fragT + ((size_t)(p * 16 + w * 4) * 32) * 64 + lane;
  const int kcmax = (len + 31) >> 5;

  #pragma unroll 4
  for (int kc = 0; kc < kcmax; ++kc) {
    const int k0 = kc * 32;
    f16x8 a[2];
    #pragma unroll
    for (int mt = 0; mt < 2; ++mt) {
      const int row = mt * 16 + lr;
      a[mt] = *(const f16x8*)&attn_lds[row][(k0 + lg * 8) ^ ((row & 7) << 3)];
    }
    #pragma unroll
    for (int nt = 0; nt < 4; ++nt) {
      f16x8 bf = btw[(nt * 32 + kc) * 64];
      acc2[0][nt] = __builtin_amdgcn_mfma_f32_16x16x32_f16(a[0], bf, acc2[0][nt], 0, 0, 0);
      acc2[1][nt] = __builtin_amdgcn_mfma_f32_16x16x32_f16(a[1], bf, acc2[1][nt], 0, 0, 0);
    }
  }

  #pragma unroll
  for (int mt = 0; mt < 2; ++mt) {
    #pragma unroll
    for (int nt = 0; nt < 4; ++nt) {
      #pragma unroll
      for (int r = 0; r < 4; ++r) {
        __builtin_nontemporal_store(
            acc2[mt][nt][r],
            &out[((size_t)p * TERM_NUM + t0 + mt * 16 + lg * 4 + r) * HID + w * 64 + nt * 16 + lr]);
      }
    }
  }
}

extern "C" void kernel_launch(void* const* d_in, const int* in_sizes, int n_in,
                              void* d_out, int out_size, void* d_ws, size_t ws_size,
                              hipStream_t stream) {
  const float* term = (const float*)d_in[0];           // 512 x 256
  const float* pro  = (const float*)d_in[1];           // 64 x 1024 x 256
  const int*   lens = (const int*)d_in[2];             // 64

  float* out  = (float*)d_out;                                   // 64*512*256
  float* attn = out + (size_t)PRO_NUM * TERM_NUM * HID;          // 64*512*1024

  f16x8* fragP = (f16x8*)d_ws;                                   // 33.55 MB
  f16x8* fragT = fragP + (size_t)PRO_NUM * 64 * 8 * 64;          // 33.55 MB

  k_prep<<<dim3(MAX_LEN / 64, PRO_NUM), 256, 0, stream>>>(pro, fragP, fragT);
  k_fused<<<dim3(PRO_NUM * (TERM_NUM / 32)), 256, 0, stream>>>(term, fragP, fragT, lens, attn, out);
}